// Round 2
// baseline (91.387 us; speedup 1.0000x reference)
//
#include <hip/hip_runtime.h>

// Problem constants (from reference): x:(32,1,512,512) f32, theta:(4,) f32
// out:(32,4,256,256) f32 but with the reference's raw .view scrambling:
//   out_flat[l*128 + b*4 + q],  l = i*256 + j (patch index), b = batch, q = qubit
#define BATCH 32
#define HH 512
#define WW 512
#define HO 256
#define WO 256
#define LTOT (HO * WO) // 65536 patches per image

__global__ __launch_bounds__(256) void quanv_kernel(const float* __restrict__ x,
                                                    const float* __restrict__ theta,
                                                    float* __restrict__ out) {
    // 16 KB staging: float4 per (l_sub, b); XOR swizzle for conflict-free b128 LDS ops
    __shared__ float4 lds[1024];

    const int tid    = threadIdx.x;
    const int l0     = blockIdx.x * 32;     // 32 consecutive patch indices per block
    const int irow   = l0 >> 8;             // l0 % 256 + 32 <= 256, so row constant in block
    const int j0     = l0 & 255;
    const int l_sub  = tid & 31;
    const int b_base = tid >> 5;            // 0..7

    // Trainable-layer rotations (uniform across patches): c/s of theta/2
    float ct[4], st[4];
#pragma unroll
    for (int q = 0; q < 4; ++q) {
        float h = theta[q] * 0.5f;
        __sincosf(h, &st[q], &ct[q]);
    }

    const int j = j0 + l_sub;
    const int roff0 = (2 * irow) * WW + 2 * j;      // within one image
    const int roff1 = roff0 + WW;

#pragma unroll
    for (int pp = 0; pp < 4; ++pp) {
        const int b = b_base + pp * 8;
        const float* xb = x + (size_t)b * (HH * WW);
        const float2 r0 = *(const float2*)(xb + roff0);  // pixels a0,a1 (row 2i)
        const float2 r1 = *(const float2*)(xb + roff1);  // pixels a2,a3 (row 2i+1)

        // Embedding: half-angle sin/cos per pixel
        float a[4] = {r0.x, r0.y, r1.x, r1.y};
        float pc[4], ps[4];
#pragma unroll
        for (int k = 0; k < 4; ++k) {
            __sincosf(a[k] * 0.5f, &ps[k], &pc[k]);
        }

        // Product state |psi> ; state index s: qubit q holds bit (8>>q)
        float amp[16];
#pragma unroll
        for (int s = 0; s < 16; ++s) {
            float v = ((s & 8) ? ps[0] : pc[0]);
            v *= ((s & 4) ? ps[1] : pc[1]);
            v *= ((s & 2) ? ps[2] : pc[2]);
            v *= ((s & 1) ? ps[3] : pc[3]);
            amp[s] = v;
        }

        // CNOT ring (0,1),(1,2),(2,3),(3,0): swap amp[s] <-> amp[s^tb] where cbit set
#pragma unroll
        for (int g = 0; g < 4; ++g) {
            const int cb = 8 >> g;
            const int tb = 8 >> ((g + 1) & 3);
#pragma unroll
            for (int s = 0; s < 16; ++s) {
                if ((s & cb) && !(s & tb)) {
                    float tmp = amp[s];
                    amp[s] = amp[s ^ tb];
                    amp[s ^ tb] = tmp;
                }
            }
        }

        // Trainable RY layer: Givens rotation on pairs along each qubit axis
#pragma unroll
        for (int q = 0; q < 4; ++q) {
            const int qb = 8 >> q;
            const float c = ct[q], sv = st[q];
#pragma unroll
            for (int s = 0; s < 16; ++s) {
                if (!(s & qb)) {
                    float v0 = amp[s], v1 = amp[s | qb];
                    amp[s]      = c * v0 - sv * v1;
                    amp[s | qb] = sv * v0 + c * v1;
                }
            }
        }

        // <Z_q> = sum p[s] * (+1 if qubit bit 0 else -1)
        float z0 = 0.f, z1 = 0.f, z2 = 0.f, z3 = 0.f;
#pragma unroll
        for (int s = 0; s < 16; ++s) {
            float p = amp[s] * amp[s];
            z0 += (s & 8) ? -p : p;
            z1 += (s & 4) ? -p : p;
            z2 += (s & 2) ? -p : p;
            z3 += (s & 1) ? -p : p;
        }

        lds[l_sub * 32 + (b ^ (l_sub & 7))] = make_float4(z0, z1, z2, z3);
    }

    __syncthreads();

    // Contiguous 16 KB output span per block: out4[l0*32 .. l0*32+1023]
    float4* out4 = (float4*)out + (size_t)l0 * 32;
#pragma unroll
    for (int k = 0; k < 4; ++k) {
        const int idx = k * 256 + tid;
        const int ls = idx >> 5, bb = idx & 31;
        out4[idx] = lds[ls * 32 + (bb ^ (ls & 7))];
    }
}

extern "C" void kernel_launch(void* const* d_in, const int* in_sizes, int n_in,
                              void* d_out, int out_size, void* d_ws, size_t ws_size,
                              hipStream_t stream) {
    const float* x     = (const float*)d_in[0];
    const float* theta = (const float*)d_in[1];
    float* out         = (float*)d_out;

    const int blocks = LTOT / 32; // 2048
    quanv_kernel<<<blocks, 256, 0, stream>>>(x, theta, out);
}